// Round 7
// baseline (160.445 us; speedup 1.0000x reference)
//
#include <hip/hip_runtime.h>
#include <math.h>

#define NBATCH 4
#define NSEQ   1024
#define DMODEL 512
#define NH     8
#define DH     64
#define MROWS  (NBATCH*NSEQ)   // 4096
#define MHALF  (DH/2)          // 32

typedef __attribute__((ext_vector_type(8))) short bf16x8;
typedef __attribute__((ext_vector_type(4))) float floatx4;

// round-to-nearest-even fp32 -> bf16 (finite inputs only)
__device__ __forceinline__ ushort f2bf(float f) {
    union { float f; uint u; } v; v.f = f;
    uint r = v.u + 0x7fffu + ((v.u >> 16) & 1u);
    return (ushort)(r >> 16);
}

// async global->LDS, 16B per lane. LDS dest must be wave-uniform base;
// lane i lands at base + 16*i (CK-style address-space casts).
__device__ __forceinline__ void g2l16(const ushort* g, ushort* l) {
    __builtin_amdgcn_global_load_lds(
        (const __attribute__((address_space(1))) uint*)g,
        (__attribute__((address_space(3))) uint*)l,
        16, 0, 0);
}

// ---------------------------------------------------------------------------
// Kernel 0 (fused prep): blocks 0..1023 angles, 1024..2047 x->bf16,
// 2048..2303 weight transpose-cast into Wt[n_global][k] bf16
// (0..511 Wq, 512..1023 Wk, 1024..1535 Wv, 1536..2047 Wo).
// ---------------------------------------------------------------------------
__global__ __launch_bounds__(256) void prep_kernel(
    const float* __restrict__ pos, const float* __restrict__ freqs,
    const float* __restrict__ x,
    const float* __restrict__ Wq, const float* __restrict__ Wk,
    const float* __restrict__ Wv, const float* __restrict__ Wo,
    float* __restrict__ cosT, float* __restrict__ sinT,
    ushort* __restrict__ xb, ushort* __restrict__ Wt)
{
    __shared__ float T[64][65];
    const int bid = blockIdx.x;
    const int tid = threadIdx.x;

    if (bid < 1024) {
        int idx = bid * 256 + tid;
        int m = idx & 31;
        int n = (idx >> 5) & 1023;
        int h = idx >> 15;
        float a = pos[n*2+0] * freqs[(h*MHALF+m)*2+0]
                + pos[n*2+1] * freqs[(h*MHALF+m)*2+1];
        cosT[idx] = cosf(a);
        sinT[idx] = sinf(a);
    } else if (bid < 2048) {
        int idx = ((bid - 1024) * 256 + tid) * 8;
        float4 a = *(const float4*)&x[idx];
        float4 b = *(const float4*)&x[idx+4];
        uint4 pk;
        pk.x = (uint)f2bf(a.x) | ((uint)f2bf(a.y) << 16);
        pk.y = (uint)f2bf(a.z) | ((uint)f2bf(a.w) << 16);
        pk.z = (uint)f2bf(b.x) | ((uint)f2bf(b.y) << 16);
        pk.w = (uint)f2bf(b.z) | ((uint)f2bf(b.w) << 16);
        *(uint4*)&xb[idx] = pk;
    } else {
        int b2 = bid - 2048;               // 0..255
        int n0g = (b2 & 31) * 64;          // 0..2047
        int k0  = (b2 >> 5) * 64;
        int mat = n0g >> 9;
        const float* W = (mat == 0) ? Wq : ((mat == 1) ? Wk : ((mat == 2) ? Wv : Wo));
        int n0 = n0g & 511;
        int c = tid & 63, r = tid >> 6;
        #pragma unroll
        for (int i = 0; i < 16; i++)
            T[r + i*4][c] = W[(k0 + r + i*4) * DMODEL + n0 + c];
        __syncthreads();
        int nl = tid >> 2;
        int kg = tid & 3;
        #pragma unroll
        for (int g = 0; g < 4; g++) {
            int kl = kg * 16 + g * 4;
            uint2 pk;
            pk.x = (uint)f2bf(T[kl+0][nl]) | ((uint)f2bf(T[kl+1][nl]) << 16);
            pk.y = (uint)f2bf(T[kl+2][nl]) | ((uint)f2bf(T[kl+3][nl]) << 16);
            *(uint2*)&Wt[(size_t)(n0g + nl) * DMODEL + k0 + kl] = pk;
        }
    }
}

// ---------------------------------------------------------------------------
// Kernel 1: QKV GEMM, m97 structure: 128x128 tile, 4 waves in 2x2 quadrants
// (64x64/wave, 16 acc tiles), BK=32, global_load_lds width-16 staging into
// unpadded row-major [128][32] LDS tiles. Per wave-K-step:
// 16 MFMA / 8 ds_read_b128 / 4 global_load_lds_dwordx4.
// Epilogue: 2 passes of 64 cols bounced via Cs[128][65] (unions with staging),
// verified R3 rotary / V-transpose logic.
// Grid (12, 32): cb covers Wt rows cb*128 (Q:0..3, K:4..7, V:8..11).
// ---------------------------------------------------------------------------
__global__ __launch_bounds__(256) void qkv_gemm(
    const ushort* __restrict__ xb, const ushort* __restrict__ Wt,
    const float* __restrict__ cosT, const float* __restrict__ sinT,
    ushort* __restrict__ Qb, ushort* __restrict__ Kb, ushort* __restrict__ Vt)
{
    __shared__ union {
        struct { ushort A[128*32]; ushort B[128*32]; } st;
        float Cs[128*65];
    } sm;

    const int cb = blockIdx.x;       // 0..11
    const int rb = blockIdx.y;       // 0..31
    const int r0 = rb * 128;
    const int ngBase = cb * 128;     // row base in Wt
    const int mat = cb >> 2;         // 0=Q 1=K 2=V

    const int tid = threadIdx.x;
    const int w = tid >> 6, l = tid & 63;
    const int lr = l & 15, lg = l >> 4;
    const int wr = w >> 1, wc = w & 1;

    const int srow  = 32*w + (l >> 2);   // staging row (inst 0)
    const int skoff = (l & 3) * 8;       // staging k-offset (elems)

    floatx4 acc[4][4];
    #pragma unroll
    for (int mt = 0; mt < 4; mt++)
        #pragma unroll
        for (int nt = 0; nt < 4; nt++)
            acc[mt][nt] = (floatx4){0.f, 0.f, 0.f, 0.f};

    for (int k0 = 0; k0 < DMODEL; k0 += 32) {
        __syncthreads();
        g2l16(&xb[(size_t)(r0 + srow) * DMODEL + k0 + skoff],          &sm.st.A[(32*w) * 32]);
        g2l16(&xb[(size_t)(r0 + srow + 16) * DMODEL + k0 + skoff],     &sm.st.A[(32*w + 16) * 32]);
        g2l16(&Wt[(size_t)(ngBase + srow) * DMODEL + k0 + skoff],      &sm.st.B[(32*w) * 32]);
        g2l16(&Wt[(size_t)(ngBase + srow + 16) * DMODEL + k0 + skoff], &sm.st.B[(32*w + 16) * 32]);
        __syncthreads();   // compiler emits vmcnt(0) drain before s_barrier

        bf16x8 af[4], bf[4];
        #pragma unroll
        for (int mt = 0; mt < 4; mt++)
            af[mt] = *(const bf16x8*)&sm.st.A[(64*wr + mt*16 + lr)*32 + lg*8];
        #pragma unroll
        for (int nt = 0; nt < 4; nt++)
            bf[nt] = *(const bf16x8*)&sm.st.B[(64*wc + nt*16 + lr)*32 + lg*8];
        #pragma unroll
        for (int mt = 0; mt < 4; mt++)
            #pragma unroll
            for (int nt = 0; nt < 4; nt++)
                acc[mt][nt] = __builtin_amdgcn_mfma_f32_16x16x32_bf16(af[mt], bf[nt], acc[mt][nt], 0, 0, 0);
    }

    // Epilogue: two 64-col passes. head = (2*cb + ch) & 7 (uniform per pass).
    #pragma unroll
    for (int ch = 0; ch < 2; ch++) {
        const int head = (2*cb + ch) & 7;
        __syncthreads();
        if (wc == ch) {
            #pragma unroll
            for (int mt = 0; mt < 4; mt++)
                #pragma unroll
                for (int nt = 0; nt < 4; nt++)
                    #pragma unroll
                    for (int r = 0; r < 4; r++)
                        sm.Cs[(64*wr + mt*16 + lg*4 + r)*65 + nt*16 + lr] = acc[mt][nt][r];
        }
        __syncthreads();

        if (mat == 2) {
            // V: Vt[((b*8+head)*64 + d)*1024 + n], pack 4 consecutive n
            int vn = tid & 31, vd = tid >> 5;
            int n0v = (r0 & 1023) + vn*4;
            int bv = r0 >> 10;
            size_t vbase = (size_t)(bv*8 + head) * 64;
            #pragma unroll
            for (int dj = 0; dj < 8; dj++) {
                int d = vd*8 + dj;
                ushort us[4];
                #pragma unroll
                for (int i = 0; i < 4; i++) us[i] = f2bf(sm.Cs[(vn*4 + i)*65 + d]);
                uint2 pk;
                pk.x = (uint)us[0] | ((uint)us[1] << 16);
                pk.y = (uint)us[2] | ((uint)us[3] << 16);
                *(uint2*)&Vt[(vbase + d)*NSEQ + n0v] = pk;
            }
        } else {
            ushort* dst = (mat == 0) ? Qb : Kb;
            int row = tid >> 1;            // 0..127
            int half = tid & 1;            // 32-col half of this pass
            int grow = r0 + row;
            int bq = grow >> 10, n = grow & 1023;
            const float* cs  = &sm.Cs[row*65 + half*32];
            const float* ct  = &cosT[((size_t)head*NSEQ + n)*MHALF + half*16];
            const float* stt = &sinT[((size_t)head*NSEQ + n)*MHALF + half*16];
            size_t ob = ((size_t)(bq*NH + head)*NSEQ + n)*DH + half*32;
            #pragma unroll
            for (int g = 0; g < 8; g++) {
                float e0 = cs[g*4+0], o0 = cs[g*4+1];
                float e1 = cs[g*4+2], o1 = cs[g*4+3];
                float c0 = ct[g*2],   s0 = stt[g*2];
                float c1 = ct[g*2+1], s1 = stt[g*2+1];
                float v0 = e0*c0 - o0*s0, v1 = e0*s0 + o0*c0;
                float v2 = e1*c1 - o1*s1, v3 = e1*s1 + o1*c1;
                uint2 pk;
                pk.x = (uint)f2bf(v0) | ((uint)f2bf(v1) << 16);
                pk.y = (uint)f2bf(v2) | ((uint)f2bf(v3) << 16);
                *(uint2*)&dst[ob + g*4] = pk;
            }
        }
    }
}

// ---------------------------------------------------------------------------
// Kernel 2: flash attention, split-K x4, no-rescale softmax, 32 queries/wave
// (unchanged from R6 — verified).
// ---------------------------------------------------------------------------
__global__ __launch_bounds__(256, 4) void attn_kernel(
    const ushort* __restrict__ Qb, const ushort* __restrict__ Kb,
    const ushort* __restrict__ Vt, float* __restrict__ Opart,
    float* __restrict__ Lsum)
{
    __shared__ ushort Ks[64 * 72];
    __shared__ ushort Vs[64 * 72];
    __shared__ ushort Ps[128 * 72];

    const int tid = threadIdx.x;
    const int w = tid >> 6, l = tid & 63;
    const int lr = l & 15, lg = l >> 4;
    const int bh = blockIdx.y, q0 = blockIdx.x * 128;
    const int z = blockIdx.z, jt0 = z * 4;

    const ushort* Qg = Qb + (size_t)bh * NSEQ * DH;
    const ushort* Kg = Kb + (size_t)bh * NSEQ * DH;
    const ushort* Vg = Vt + (size_t)bh * DH * NSEQ;

    bf16x8 qf[2][2];
    #pragma unroll
    for (int qc = 0; qc < 2; qc++)
        #pragma unroll
        for (int ks = 0; ks < 2; ks++)
            qf[qc][ks] = *(const bf16x8*)(Qg +
                (size_t)(q0 + 32*w + 16*qc + lr) * DH + ks*32 + lg*8);

    floatx4 ot[4][2];
    #pragma unroll
    for (int dt = 0; dt < 4; dt++)
        #pragma unroll
        for (int qc = 0; qc < 2; qc++)
            ot[dt][qc] = (floatx4){0.f, 0.f, 0.f, 0.f};
    float rsum[2] = {0.f, 0.f};
    const float cexp = 0.2550348550f;    // log2(e)/sqrt(32)

    const int sr = tid >> 2;
    const int sc = (tid & 3) * 16;

    const ushort* kp = Kg + (size_t)(jt0*64 + sr) * DH + sc;
    uint4 ka  = *(const uint4*)kp;
    uint4 kb2 = *(const uint4*)(kp + 8);
    const ushort* vp = Vg + (size_t)sr * NSEQ + jt0*64 + sc;
    uint4 va  = *(const uint4*)vp;
    uint4 vb2 = *(const uint4*)(vp + 8);

    for (int jt = jt0; jt < jt0 + 4; jt++) {
        __syncthreads();
        *(uint4*)&Ks[sr*72 + sc]     = ka;
        *(uint4*)&Ks[sr*72 + sc + 8] = kb2;
        *(uint4*)&Vs[sr*72 + sc]     = va;
        *(uint4*)&Vs[sr*72 + sc + 8] = vb2;
        __syncthreads();

        if (jt < jt0 + 3) {
            const ushort* kn = Kg + (size_t)((jt+1)*64 + sr) * DH + sc;
            ka  = *(const uint4*)kn;
            kb2 = *(const uint4*)(kn + 8);
            const ushort* vn = Vg + (size_t)sr * NSEQ + (jt+1)*64 + sc;
            va  = *(const uint4*)vn;
            vb2 = *(const uint4*)(vn + 8);
        }

        #pragma unroll
        for (int jm = 0; jm < 4; jm++) {
            bf16x8 a0 = *(const bf16x8*)&Ks[(jm*16 + lr)*72 + lg*8];
            bf16x8 a1 = *(const bf16x8*)&Ks[(jm*16 + lr)*72 + 32 + lg*8];
            #pragma unroll
            for (int qc = 0; qc < 2; qc++) {
                floatx4 s = (floatx4){0.f, 0.f, 0.f, 0.f};
                s = __builtin_amdgcn_mfma_f32_16x16x32_bf16(a0, qf[qc][0], s, 0, 0, 0);
                s = __builtin_amdgcn_mfma_f32_16x16x32_bf16(a1, qf[qc][1], s, 0, 0, 0);
                ushort us[4];
                #pragma unroll
                for (int r = 0; r < 4; r++) {
                    float p = exp2f(s[r] * cexp);
                    rsum[qc] += p;
                    us[r] = f2bf(p);
                }
                uint2 pk;
                pk.x = (uint)us[0] | ((uint)us[1] << 16);
                pk.y = (uint)us[2] | ((uint)us[3] << 16);
                *(uint2*)&Ps[(32*w + 16*qc + lr)*72 + jm*16 + lg*4] = pk;
            }
        }

        bf16x8 pf[2][2];
        #pragma unroll
        for (int qc = 0; qc < 2; qc++)
            #pragma unroll
            for (int ks = 0; ks < 2; ks++)
                pf[qc][ks] = *(const bf16x8*)&Ps[(32*w + 16*qc + lr)*72 + ks*32 + lg*8];
        #pragma unroll
        for (int dt = 0; dt < 4; dt++) {
            bf16x8 v0 = *(const bf16x8*)&Vs[(dt*16 + lr)*72 + lg*8];
            bf16x8 v1 = *(const bf16x8*)&Vs[(dt*16 + lr)*72 + 32 + lg*8];
            #pragma unroll
            for (int qc = 0; qc < 2; qc++) {
                ot[dt][qc] = __builtin_amdgcn_mfma_f32_16x16x32_bf16(v0, pf[qc][0], ot[dt][qc], 0, 0, 0);
                ot[dt][qc] = __builtin_amdgcn_mfma_f32_16x16x32_bf16(v1, pf[qc][1], ot[dt][qc], 0, 0, 0);
            }
        }
    }

    #pragma unroll
    for (int qc = 0; qc < 2; qc++) {
        rsum[qc] += __shfl_xor(rsum[qc], 16, 64);
        rsum[qc] += __shfl_xor(rsum[qc], 32, 64);
    }

    #pragma unroll
    for (int qc = 0; qc < 2; qc++) {
        int n = q0 + 32*w + 16*qc + lr;
        size_t obase = ((size_t)(z * 32 + bh) * NSEQ + n) * DH;
        #pragma unroll
        for (int dt = 0; dt < 4; dt++)
            *(floatx4*)&Opart[obase + dt*16 + lg*4] = ot[dt][qc];
        if (lg == 0)
            Lsum[(size_t)(z * 32 + bh) * NSEQ + n] = rsum[qc];
    }
}

// ---------------------------------------------------------------------------
// Kernel 2b: combine the 4 split-K slices -> Obb bf16 (unchanged from R6).
// ---------------------------------------------------------------------------
__global__ __launch_bounds__(256) void combine_kernel(
    const float* __restrict__ Op, const float* __restrict__ Ls,
    ushort* __restrict__ Obb)
{
    int idx = blockIdx.x * 256 + threadIdx.x;
    int qi = idx >> 2;
    int dp = (idx & 3) << 4;
    float inv = 1.f / (Ls[qi] + Ls[32768 + qi] + Ls[65536 + qi] + Ls[98304 + qi]);
    const float* p0 = Op + (size_t)qi * 64 + dp;
    const size_t zs = (size_t)32768 * 64;
    ushort* po = Obb + (size_t)qi * 64 + dp;
    #pragma unroll
    for (int g = 0; g < 4; g++) {
        float4 u0 = *(const float4*)(p0 + g*4);
        float4 u1 = *(const float4*)(p0 + zs + g*4);
        float4 u2 = *(const float4*)(p0 + 2*zs + g*4);
        float4 u3 = *(const float4*)(p0 + 3*zs + g*4);
        float sx = (u0.x + u1.x + u2.x + u3.x) * inv;
        float sy = (u0.y + u1.y + u2.y + u3.y) * inv;
        float sz = (u0.z + u1.z + u2.z + u3.z) * inv;
        float sw = (u0.w + u1.w + u2.w + u3.w) * inv;
        uint2 pk;
        pk.x = (uint)f2bf(sx) | ((uint)f2bf(sy) << 16);
        pk.y = (uint)f2bf(sz) | ((uint)f2bf(sw) << 16);
        *(uint2*)(po + g*4) = pk;
    }
}

// ---------------------------------------------------------------------------
// Kernel 3: output projection, m97 structure: 128x128 tile, BK=32,
// global_load_lds staging; A gathered from Obb [bh][n][d] (BK within a head).
// Direct coalesced dword stores from C-frags (m97-style epilogue).
// Grid (4, 32).
// ---------------------------------------------------------------------------
__global__ __launch_bounds__(256) void out_gemm(
    const ushort* __restrict__ Obb, const ushort* __restrict__ Wt,
    float* __restrict__ out)
{
    __shared__ struct { ushort A[128*32]; ushort B[128*32]; } sm;

    const int cb = blockIdx.x;       // 0..3
    const int rb = blockIdx.y;       // 0..31
    const int r0 = rb * 128;
    const int c0 = cb * 128;
    const int ngBase = 1536 + c0;    // Wo rows in Wt

    const int tid = threadIdx.x;
    const int w = tid >> 6, l = tid & 63;
    const int lr = l & 15, lg = l >> 4;
    const int wr = w >> 1, wc = w & 1;

    const int srow  = 32*w + (l >> 2);
    const int skoff = (l & 3) * 8;

    const int b0 = r0 >> 10;
    const int nsBase = (r0 & 1023) + srow;

    floatx4 acc[4][4];
    #pragma unroll
    for (int mt = 0; mt < 4; mt++)
        #pragma unroll
        for (int nt = 0; nt < 4; nt++)
            acc[mt][nt] = (floatx4){0.f, 0.f, 0.f, 0.f};

    for (int k0 = 0; k0 < DMODEL; k0 += 32) {
        const int h = k0 >> 6;
        const int d0 = (k0 & 63) + skoff;
        const size_t abase = (size_t)(b0*NH + h) * NSEQ;
        __syncthreads();
        g2l16(&Obb[(abase + nsBase) * DH + d0],        &sm.A[(32*w) * 32]);
        g2l16(&Obb[(abase + nsBase + 16) * DH + d0],   &sm.A[(32*w + 16) * 32]);
        g2l16(&Wt[(size_t)(ngBase + srow) * DMODEL + k0 + skoff],      &sm.B[(32*w) * 32]);
        g2l16(&Wt[(size_t)(ngBase + srow + 16) * DMODEL + k0 + skoff], &sm.B[(32*w + 16) * 32]);
        __syncthreads();

        bf16x8 af[4], bf[4];
        #pragma unroll
        for (int mt = 0; mt < 4; mt++)
            af[mt] = *(const bf16x8*)&sm.A[(64*wr + mt*16 + lr)*32 + lg*8];
        #pragma unroll
        for (int nt = 0; nt < 4; nt++)
            bf[nt] = *(const bf16x8*)&sm.B[(64*wc + nt*16 + lr)*32 + lg*8];
        #pragma unroll
        for (int mt = 0; mt < 4; mt++)
            #pragma unroll
            for (int nt = 0; nt < 4; nt++)
                acc[mt][nt] = __builtin_amdgcn_mfma_f32_16x16x32_bf16(af[mt], bf[nt], acc[mt][nt], 0, 0, 0);
    }

    #pragma unroll
    for (int mt = 0; mt < 4; mt++)
        #pragma unroll
        for (int nt = 0; nt < 4; nt++)
            #pragma unroll
            for (int r = 0; r < 4; r++)
                out[(size_t)(r0 + 64*wr + mt*16 + lg*4 + r) * DMODEL
                    + c0 + 64*wc + nt*16 + lr] = acc[mt][nt][r];
}

// ---------------------------------------------------------------------------
extern "C" void kernel_launch(void* const* d_in, const int* in_sizes, int n_in,
                              void* d_out, int out_size, void* d_ws, size_t ws_size,
                              hipStream_t stream) {
    const float* x         = (const float*)d_in[0];
    const float* positions = (const float*)d_in[1];
    const float* Wq        = (const float*)d_in[2];
    const float* Wk        = (const float*)d_in[3];
    const float* Wv        = (const float*)d_in[4];
    const float* Wo        = (const float*)d_in[5];
    // d_in[6] = U : unused — QR of a full-rank square matrix is a complete
    // orthogonal basis, so P = Uq Uq^T = I and the projection is a no-op.
    const float* freqs     = (const float*)d_in[7];
    float* out = (float*)d_out;

    float*  ws    = (float*)d_ws;
    float*  cosT  = ws;                                 // 262144 f32
    float*  sinT  = cosT + NH*NSEQ*MHALF;               // 262144 f32
    float*  Opart = sinT + NH*NSEQ*MHALF;               // 4*2097152 f32
    float*  Lsum  = Opart + 4*(size_t)NBATCH*NH*NSEQ*DH;  // 4*32768 f32
    ushort* xb    = (ushort*)(Lsum + 4*(size_t)NBATCH*NH*NSEQ);  // 2M bf16
    ushort* Wt    = xb + (size_t)MROWS*DMODEL;          // 2048*512 bf16
    ushort* Qb    = Wt + (size_t)2048*DMODEL;
    ushort* Kb    = Qb + (size_t)NBATCH*NH*NSEQ*DH;
    ushort* Vt    = Kb + (size_t)NBATCH*NH*NSEQ*DH;
    ushort* Obb   = Vt + (size_t)NBATCH*NH*NSEQ*DH;

    prep_kernel<<<dim3(2304), 256, 0, stream>>>(positions, freqs, x, Wq, Wk, Wv, Wo,
                                                cosT, sinT, xb, Wt);
    qkv_gemm<<<dim3(12, 32), 256, 0, stream>>>(xb, Wt, cosT, sinT, Qb, Kb, Vt);
    attn_kernel<<<dim3(8, 32, 4), 256, 0, stream>>>(Qb, Kb, Vt, Opart, Lsum);
    combine_kernel<<<dim3(512), 256, 0, stream>>>(Opart, Lsum, Obb);
    out_gemm<<<dim3(4, 32), 256, 0, stream>>>(Obb, Wt, out);
}